// Round 2
// baseline (724.878 us; speedup 1.0000x reference)
//
#include <hip/hip_runtime.h>

typedef unsigned int uint;
typedef unsigned short ushort;
typedef __attribute__((ext_vector_type(4))) float f32x4;
typedef __attribute__((ext_vector_type(8))) _Float16 f16x8;

#define HQ 512
#define BN_EPS 1e-5f

// ---------------- fp16 <-> fp32 helpers ----------------
__device__ __forceinline__ ushort f2h(float f) {
  union { ushort s; _Float16 h; } u; u.h = (_Float16)f; return u.s;
}
__device__ __forceinline__ float h2f(ushort s) {
  union { ushort s; _Float16 h; } u; u.s = s; return (float)u.h;
}
__device__ __forceinline__ void unpack2(uint v, float& a, float& b) {
  union { uint u; _Float16 h[2]; } x; x.u = v; a = (float)x.h[0]; b = (float)x.h[1];
}
__device__ __forceinline__ uint pack2(float a, float b) {
  union { uint u; _Float16 h[2]; } x; x.h[0] = (_Float16)a; x.h[1] = (_Float16)b; return x.u;
}
// split fp32 v into hi (fp16) and lo (fp16 of residual); v ≈ hi + lo with ~2^-22 rel err
__device__ __forceinline__ void split2(float a, float b, uint& hi, uint& lo) {
  float ah = h2f(f2h(a)), bh = h2f(f2h(b));
  hi = pack2(ah, bh);
  lo = pack2(a - ah, b - bh);
}

// ---------------- async global->LDS (16B/lane) ----------------
__device__ __forceinline__ void gload_lds16(const ushort* g, ushort* l) {
  __builtin_amdgcn_global_load_lds(
      (const __attribute__((address_space(1))) void*)(const void*)g,
      (__attribute__((address_space(3))) void*)(void*)l,
      16, 0, 0);
}

// ---------------- edge-index width detection ----------------
__global__ void detect_idx_kernel(const int* __restrict__ idx, int twoE, int* flag) {
  __shared__ int ok;
  if (threadIdx.x == 0) ok = 1;
  __syncthreads();
  for (int i = threadIdx.x; i < 2048; i += blockDim.x) {
    int p = 2 * i + 1;
    if (p < twoE && idx[p] != 0) ok = 0;
  }
  __syncthreads();
  if (threadIdx.x == 0) flag[0] = ok;   // 1 => int64 storage, 0 => int32
}

__device__ __forceinline__ int edge_at(const int* __restrict__ idx, int pos, int is64) {
  return is64 ? idx[2 * pos] : idx[pos];
}

// ---------------- CSR build ----------------
__global__ void degree_kernel(const int* __restrict__ idx, int E, const int* __restrict__ flag,
                              int* __restrict__ row_start) {
  int e = blockIdx.x * blockDim.x + threadIdx.x;
  if (e >= E) return;
  int is64 = flag[0];
  int d = edge_at(idx, E + e, is64);
  atomicAdd(&row_start[d + 1], 1);
}

__global__ void scan_kernel(int* __restrict__ data, int n) {  // inclusive scan over n+1 entries
  __shared__ int sh[1024];
  __shared__ int carry;
  if (threadIdx.x == 0) carry = 0;
  __syncthreads();
  for (int base = 0; base < n + 1; base += 1024) {
    int i = base + threadIdx.x;
    int v = (i < n + 1) ? data[i] : 0;
    sh[threadIdx.x] = v;
    __syncthreads();
    for (int off = 1; off < 1024; off <<= 1) {
      int t = (threadIdx.x >= (unsigned)off) ? sh[threadIdx.x - off] : 0;
      __syncthreads();
      sh[threadIdx.x] += t;
      __syncthreads();
    }
    int inc = sh[threadIdx.x] + carry;
    if (i < n + 1) data[i] = inc;
    __syncthreads();
    if (threadIdx.x == 0) carry += sh[1023];
    __syncthreads();
  }
}

__global__ void scatter_kernel(const int* __restrict__ idx, int E, const int* __restrict__ flag,
                               const int* __restrict__ row_start, int* __restrict__ cursor,
                               int* __restrict__ csr) {
  int e = blockIdx.x * blockDim.x + threadIdx.x;
  if (e >= E) return;
  int is64 = flag[0];
  int s = edge_at(idx, e, is64);
  int d = edge_at(idx, E + e, is64);
  int pos = atomicAdd(&cursor[d], 1);
  csr[row_start[d] + pos] = s;
}

// ---------------- weight / input prep (fp32 -> fp16 hi/lo) ----------------
__global__ void prep_weights_kernel(const float* __restrict__ lin0_w, const float* __restrict__ w1,
                                    const float* __restrict__ w2, ushort* __restrict__ wH,
                                    ushort* __restrict__ wL, int totalw) {
  int i4 = (blockIdx.x * blockDim.x + threadIdx.x) * 4;
  if (i4 >= totalw) return;
  const int W = HQ * HQ;
  const float* src; int off;
  if (i4 < W)          { src = lin0_w; off = i4; }
  else if (i4 < 4 * W) { src = w1;     off = i4 - W; }
  else                 { src = w2;     off = i4 - 4 * W; }
  float4 v = *(const float4*)(src + off);
  uint2 ph, pl;
  split2(v.x, v.y, ph.x, pl.x);
  split2(v.z, v.w, ph.y, pl.y);
  *(uint2*)(wH + i4) = ph;
  *(uint2*)(wL + i4) = pl;
}

__global__ void prep_x_kernel(const float* __restrict__ x, ushort* __restrict__ xH,
                              ushort* __restrict__ xL, float* __restrict__ out0, int N, int MP) {
  int i4 = (blockIdx.x * blockDim.x + threadIdx.x) * 4;
  if (i4 >= MP * HQ) return;
  int row = i4 >> 9;
  uint2 ph, pl;
  if (row < N) {
    float4 v = *(const float4*)(x + i4);
    *(float4*)(out0 + i4) = v;                       // embs[0] = x (exact fp32 copy)
    split2(v.x, v.y, ph.x, pl.x);
    split2(v.z, v.w, ph.y, pl.y);
  } else {
    ph.x = ph.y = pl.x = pl.y = 0u;                  // zero pad rows
  }
  *(uint2*)(xH + i4) = ph;
  *(uint2*)(xL + i4) = pl;
}

// ---------------- GIN aggregation: z[n] = h[n] + sum_{j in nbr(n)} h[j] ----------------
__global__ void gather_kernel(const ushort* __restrict__ hH, const ushort* __restrict__ hL,
                              ushort* __restrict__ zH, ushort* __restrict__ zL,
                              const int* __restrict__ row_start, const int* __restrict__ csr) {
  const int n = blockIdx.x;
  const int c = threadIdx.x * 8;   // 64 lanes * 8 fp16 = 512
  float a[8];
  {
    uint4 vh = *(const uint4*)(hH + (size_t)n * HQ + c);
    uint4 vl = *(const uint4*)(hL + (size_t)n * HQ + c);
    float t0, t1, u0, u1;
    unpack2(vh.x, t0, t1); unpack2(vl.x, u0, u1); a[0] = t0 + u0; a[1] = t1 + u1;
    unpack2(vh.y, t0, t1); unpack2(vl.y, u0, u1); a[2] = t0 + u0; a[3] = t1 + u1;
    unpack2(vh.z, t0, t1); unpack2(vl.z, u0, u1); a[4] = t0 + u0; a[5] = t1 + u1;
    unpack2(vh.w, t0, t1); unpack2(vl.w, u0, u1); a[6] = t0 + u0; a[7] = t1 + u1;
  }
  const int s = row_start[n], e = row_start[n + 1];
  for (int j = s; j < e; ++j) {
    int src = csr[j];
    uint4 vh = *(const uint4*)(hH + (size_t)src * HQ + c);
    uint4 vl = *(const uint4*)(hL + (size_t)src * HQ + c);
    float t0, t1, u0, u1;
    unpack2(vh.x, t0, t1); unpack2(vl.x, u0, u1); a[0] += t0 + u0; a[1] += t1 + u1;
    unpack2(vh.y, t0, t1); unpack2(vl.y, u0, u1); a[2] += t0 + u0; a[3] += t1 + u1;
    unpack2(vh.z, t0, t1); unpack2(vl.z, u0, u1); a[4] += t0 + u0; a[5] += t1 + u1;
    unpack2(vh.w, t0, t1); unpack2(vl.w, u0, u1); a[6] += t0 + u0; a[7] += t1 + u1;
  }
  uint4 oh, ol;
  split2(a[0], a[1], oh.x, ol.x);
  split2(a[2], a[3], oh.y, ol.y);
  split2(a[4], a[5], oh.z, ol.z);
  split2(a[6], a[7], oh.w, ol.w);
  *(uint4*)(zH + (size_t)n * HQ + c) = oh;
  *(uint4*)(zL + (size_t)n * HQ + c) = ol;
}

// ---------------- GEMM: C[m,n] = A[m,:] . W[n,:] + bias[n], optional ReLU ----------------
// double-fp16: A = AH+AL, W = WH+WL; C ≈ AH·WH + AL·WH + AH·WL (fp32 acc).
// 128x128 tile, BK=32, 4 waves (2x2 of 64x64), mfma_f32_16x16x32_f16.
template <int RELU>
__launch_bounds__(256)
__global__ void gemm3_kernel(const ushort* __restrict__ AH, const ushort* __restrict__ AL,
                             const ushort* __restrict__ WH, const ushort* __restrict__ WL,
                             const float* __restrict__ bias,
                             ushort* __restrict__ CH, ushort* __restrict__ CL) {
  __shared__ ushort AsH[128 * 32];
  __shared__ ushort AsL[128 * 32];
  __shared__ ushort BsH[128 * 32];
  __shared__ ushort BsL[128 * 32];
  const int tid  = threadIdx.x;
  const int lane = tid & 63;
  const int wave = tid >> 6;
  const int m0 = blockIdx.x * 128;
  const int n0 = blockIdx.y * 128;
  const int wm = (wave >> 1) * 64;
  const int wn = (wave & 1) * 64;

  f32x4 acc[4][4];
#pragma unroll
  for (int i = 0; i < 4; ++i)
#pragma unroll
    for (int j = 0; j < 4; ++j) acc[i][j] = (f32x4){0.f, 0.f, 0.f, 0.f};

  const int fr = lane & 15;
  const int kb = lane >> 4;

  for (int kt = 0; kt < HQ; kt += 32) {
#pragma unroll
    for (int q = 0; q < 2; ++q) {
      const int ch  = q * 256 + tid;       // chunk id: row = ch>>2, col = (ch&3)*8
      const int row = ch >> 2;
      const int col = (ch & 3) * 8;
      const size_t ga = (size_t)(m0 + row) * HQ + kt + col;
      const size_t gb = (size_t)(n0 + row) * HQ + kt + col;
      ushort* la = (ushort*)((size_t)(q * 256 + wave * 64) * 8);
      gload_lds16(AH + ga, AsH + (size_t)(q * 256 + wave * 64) * 8);
      gload_lds16(AL + ga, AsL + (size_t)(q * 256 + wave * 64) * 8);
      gload_lds16(WH + gb, BsH + (size_t)(q * 256 + wave * 64) * 8);
      gload_lds16(WL + gb, BsL + (size_t)(q * 256 + wave * 64) * 8);
      (void)la;
    }
    __syncthreads();
    f16x8 afH[4], afL[4], bfH[4], bfL[4];
#pragma unroll
    for (int i = 0; i < 4; ++i) {
      afH[i] = *(const f16x8*)&AsH[(wm + i * 16 + fr) * 32 + kb * 8];
      afL[i] = *(const f16x8*)&AsL[(wm + i * 16 + fr) * 32 + kb * 8];
    }
#pragma unroll
    for (int j = 0; j < 4; ++j) {
      bfH[j] = *(const f16x8*)&BsH[(wn + j * 16 + fr) * 32 + kb * 8];
      bfL[j] = *(const f16x8*)&BsL[(wn + j * 16 + fr) * 32 + kb * 8];
    }
#pragma unroll
    for (int i = 0; i < 4; ++i)
#pragma unroll
      for (int j = 0; j < 4; ++j)
        acc[i][j] = __builtin_amdgcn_mfma_f32_16x16x32_f16(afH[i], bfH[j], acc[i][j], 0, 0, 0);
#pragma unroll
    for (int i = 0; i < 4; ++i)
#pragma unroll
      for (int j = 0; j < 4; ++j)
        acc[i][j] = __builtin_amdgcn_mfma_f32_16x16x32_f16(afL[i], bfH[j], acc[i][j], 0, 0, 0);
#pragma unroll
    for (int i = 0; i < 4; ++i)
#pragma unroll
      for (int j = 0; j < 4; ++j)
        acc[i][j] = __builtin_amdgcn_mfma_f32_16x16x32_f16(afH[i], bfL[j], acc[i][j], 0, 0, 0);
    __syncthreads();
  }

  // epilogue: D col = lane&15, row = (lane>>4)*4 + r   [guide §3, m89/m91-verified]
#pragma unroll
  for (int j = 0; j < 4; ++j) {
    const int col = n0 + wn + j * 16 + fr;
    const float b = bias[col];
#pragma unroll
    for (int i = 0; i < 4; ++i) {
      const int mb = m0 + wm + i * 16 + kb * 4;
#pragma unroll
      for (int r = 0; r < 4; ++r) {
        float v = acc[i][j][r] + b;
        if (RELU) v = fmaxf(v, 0.f);
        ushort hi = f2h(v);
        float  lo = v - h2f(hi);
        CH[(size_t)(mb + r) * HQ + col] = hi;
        CL[(size_t)(mb + r) * HQ + col] = f2h(lo);
      }
    }
  }
}

// ---------------- BatchNorm statistics ----------------
__global__ void bn_stats_kernel(const ushort* __restrict__ zH, const ushort* __restrict__ zL,
                                float* __restrict__ sums, int N, int rows_per) {
  const int c2 = threadIdx.x;  // column pair 2*c2, 2*c2+1
  const int r0 = blockIdx.x * rows_per;
  const int r1 = (r0 + rows_per < N) ? (r0 + rows_per) : N;
  float s0 = 0.f, s1 = 0.f, q0 = 0.f, q1 = 0.f;
  for (int r = r0; r < r1; ++r) {
    uint vh = *(const uint*)(zH + (size_t)r * HQ + 2 * c2);
    uint vl = *(const uint*)(zL + (size_t)r * HQ + 2 * c2);
    float a, b, ua, ub; unpack2(vh, a, b); unpack2(vl, ua, ub);
    a += ua; b += ub;
    s0 += a; q0 += a * a; s1 += b; q1 += b * b;
  }
  atomicAdd(&sums[2 * c2], s0);
  atomicAdd(&sums[2 * c2 + 1], s1);
  atomicAdd(&sums[HQ + 2 * c2], q0);
  atomicAdd(&sums[HQ + 2 * c2 + 1], q1);
}

__global__ void bn_finalize_kernel(const float* __restrict__ sums, const float* __restrict__ gamma,
                                   const float* __restrict__ beta, float* __restrict__ scale,
                                   float* __restrict__ shift, int N) {
  int c = threadIdx.x;
  if (c < HQ) {
    float inv_n = 1.f / (float)N;
    float mu = sums[c] * inv_n;
    float var = fmaxf(sums[HQ + c] * inv_n - mu * mu, 0.f);
    float sc = gamma[c] * rsqrtf(var + BN_EPS);
    scale[c] = sc;
    shift[c] = beta[c] - mu * sc;
  }
}

__global__ void bn_apply_tanh_kernel(const ushort* __restrict__ zH, const ushort* __restrict__ zL,
                                     const float* __restrict__ scale, const float* __restrict__ shift,
                                     float* __restrict__ outp, ushort* __restrict__ hH,
                                     ushort* __restrict__ hL, int total) {
  int i8 = (blockIdx.x * blockDim.x + threadIdx.x) * 8;
  if (i8 >= total) return;
  int c0 = i8 & (HQ - 1);
  uint4 vh = *(const uint4*)(zH + i8);
  uint4 vl = *(const uint4*)(zL + i8);
  float a[8];
  {
    float t0, t1, u0, u1;
    unpack2(vh.x, t0, t1); unpack2(vl.x, u0, u1); a[0] = t0 + u0; a[1] = t1 + u1;
    unpack2(vh.y, t0, t1); unpack2(vl.y, u0, u1); a[2] = t0 + u0; a[3] = t1 + u1;
    unpack2(vh.z, t0, t1); unpack2(vl.z, u0, u1); a[4] = t0 + u0; a[5] = t1 + u1;
    unpack2(vh.w, t0, t1); unpack2(vl.w, u0, u1); a[6] = t0 + u0; a[7] = t1 + u1;
  }
  float4 sA = *(const float4*)(scale + c0);
  float4 sB = *(const float4*)(scale + c0 + 4);
  float4 hA = *(const float4*)(shift + c0);
  float4 hB = *(const float4*)(shift + c0 + 4);
  float y[8];
  y[0] = tanhf(fmaf(a[0], sA.x, hA.x));
  y[1] = tanhf(fmaf(a[1], sA.y, hA.y));
  y[2] = tanhf(fmaf(a[2], sA.z, hA.z));
  y[3] = tanhf(fmaf(a[3], sA.w, hA.w));
  y[4] = tanhf(fmaf(a[4], sB.x, hB.x));
  y[5] = tanhf(fmaf(a[5], sB.y, hB.y));
  y[6] = tanhf(fmaf(a[6], sB.z, hB.z));
  y[7] = tanhf(fmaf(a[7], sB.w, hB.w));
  *(float4*)(outp + i8)     = make_float4(y[0], y[1], y[2], y[3]);
  *(float4*)(outp + i8 + 4) = make_float4(y[4], y[5], y[6], y[7]);
  uint4 oh, ol;
  split2(y[0], y[1], oh.x, ol.x);
  split2(y[2], y[3], oh.y, ol.y);
  split2(y[4], y[5], oh.z, ol.z);
  split2(y[6], y[7], oh.w, ol.w);
  *(uint4*)(hH + i8) = oh;
  *(uint4*)(hL + i8) = ol;
}

// ---------------- launcher ----------------
extern "C" void kernel_launch(void* const* d_in, const int* in_sizes, int n_in,
                              void* d_out, int out_size, void* d_ws, size_t ws_size,
                              hipStream_t stream) {
  const float* x      = (const float*)d_in[0];
  const int*   idx    = (const int*)  d_in[1];
  const float* lin0_w = (const float*)d_in[2];
  const float* lin0_b = (const float*)d_in[3];
  const float* w1     = (const float*)d_in[4];
  const float* b1     = (const float*)d_in[5];
  const float* w2     = (const float*)d_in[6];
  const float* b2     = (const float*)d_in[7];
  const float* gamma  = (const float*)d_in[8];
  const float* beta   = (const float*)d_in[9];
  float* out = (float*)d_out;

  const int N    = in_sizes[0] / HQ;           // 10000
  const int twoE = in_sizes[1];                // 2*E
  const int E    = twoE / 2;
  const int L    = in_sizes[4] / (HQ * HQ);    // 3
  const int MT   = (N + 127) / 128;            // 79
  const int MP   = MT * 128;                   // 10112 (padded M)
  const size_t NH = (size_t)N * HQ;
  const size_t T  = (size_t)MP * HQ;           // padded tensor elems

  // workspace carve (all 16B-aligned)
  char* wsp = (char*)d_ws;
  int*    flag  = (int*)wsp;
  ushort* hbH   = (ushort*)(wsp + 256);
  ushort* hbL   = hbH + T;
  ushort* zAH   = hbL + T;
  ushort* zAL   = zAH + T;
  ushort* zBH   = zAL + T;
  ushort* zBL   = zBH + T;
  ushort* wHp   = zBL + T;
  ushort* wLp   = wHp + (size_t)(1 + 2 * L) * HQ * HQ;
  int*    row_start = (int*)(wLp + (size_t)(1 + 2 * L) * HQ * HQ);
  int*    cursor    = row_start + (N + 1);
  int*    csr       = cursor + N;
  float*  bnsums    = (float*)(csr + E);
  float*  bnscale   = bnsums + 2 * HQ;
  float*  bnshift   = bnscale + HQ;

  hipMemsetAsync(row_start, 0, (size_t)(2 * N + 1) * sizeof(int), stream);
  detect_idx_kernel<<<1, 256, 0, stream>>>(idx, twoE, flag);

  const int totalw = (1 + 2 * L) * HQ * HQ;
  prep_weights_kernel<<<(totalw / 4 + 255) / 256, 256, 0, stream>>>(lin0_w, w1, w2, wHp, wLp, totalw);
  prep_x_kernel<<<((int)(T / 4) + 255) / 256, 256, 0, stream>>>(x, zAH, zAL, out, N, MP);

  degree_kernel<<<(E + 255) / 256, 256, 0, stream>>>(idx, E, flag, row_start);
  scan_kernel<<<1, 1024, 0, stream>>>(row_start, N);
  scatter_kernel<<<(E + 255) / 256, 256, 0, stream>>>(idx, E, flag, row_start, cursor, csr);

  // h0 = x @ lin0_w.T + lin0_b   (no activation)
  gemm3_kernel<0><<<dim3(MT, HQ / 128), 256, 0, stream>>>(zAH, zAL, wHp, wLp, lin0_b, hbH, hbL);

  const int rows_per = (N + 39) / 40;
  for (int l = 0; l < L; ++l) {
    gather_kernel<<<N, 64, 0, stream>>>(hbH, hbL, zAH, zAL, row_start, csr);
    gemm3_kernel<1><<<dim3(MT, HQ / 128), 256, 0, stream>>>(
        zAH, zAL, wHp + (size_t)(1 + l) * HQ * HQ, wLp + (size_t)(1 + l) * HQ * HQ,
        b1 + (size_t)l * HQ, zBH, zBL);
    gemm3_kernel<1><<<dim3(MT, HQ / 128), 256, 0, stream>>>(
        zBH, zBL, wHp + (size_t)(1 + L + l) * HQ * HQ, wLp + (size_t)(1 + L + l) * HQ * HQ,
        b2 + (size_t)l * HQ, zAH, zAL);
    hipMemsetAsync(bnsums, 0, 2 * HQ * sizeof(float), stream);
    bn_stats_kernel<<<40, 256, 0, stream>>>(zAH, zAL, bnsums, N, rows_per);
    bn_finalize_kernel<<<1, HQ, 0, stream>>>(bnsums, gamma + (size_t)l * HQ, beta + (size_t)l * HQ,
                                             bnscale, bnshift, N);
    bn_apply_tanh_kernel<<<((int)(NH / 8) + 255) / 256, 256, 0, stream>>>(
        zAH, zAL, bnscale, bnshift, out + (size_t)(l + 1) * NH, hbH, hbL, (int)NH);
  }
}

// Round 3
// 513.657 us; speedup vs baseline: 1.4112x; 1.4112x over previous
//
#include <hip/hip_runtime.h>

typedef unsigned int uint;
typedef unsigned short ushort;
typedef __attribute__((ext_vector_type(4))) float f32x4;
typedef __attribute__((ext_vector_type(8))) _Float16 f16x8;

#define HQ 512
#define BN_EPS 1e-5f

// ---------------- fp16 <-> fp32 helpers ----------------
__device__ __forceinline__ ushort f2h(float f) {
  union { ushort s; _Float16 h; } u; u.h = (_Float16)f; return u.s;
}
__device__ __forceinline__ float h2f(ushort s) {
  union { ushort s; _Float16 h; } u; u.s = s; return (float)u.h;
}
__device__ __forceinline__ void unpack2(uint v, float& a, float& b) {
  union { uint u; _Float16 h[2]; } x; x.u = v; a = (float)x.h[0]; b = (float)x.h[1];
}
__device__ __forceinline__ uint pack2(float a, float b) {
  union { uint u; _Float16 h[2]; } x; x.h[0] = (_Float16)a; x.h[1] = (_Float16)b; return x.u;
}
// split fp32 v into hi (fp16) and lo (fp16 of residual); v ≈ hi + lo with ~2^-22 rel err
__device__ __forceinline__ void split2(float a, float b, uint& hi, uint& lo) {
  float ah = h2f(f2h(a)), bh = h2f(f2h(b));
  hi = pack2(ah, bh);
  lo = pack2(a - ah, b - bh);
}

// ---------------- async global->LDS (16B/lane) ----------------
__device__ __forceinline__ void gload_lds16(const ushort* g, ushort* l) {
  __builtin_amdgcn_global_load_lds(
      (const __attribute__((address_space(1))) void*)(const void*)g,
      (__attribute__((address_space(3))) void*)(void*)l,
      16, 0, 0);
}

// ---------------- edge-index width detection ----------------
__global__ void detect_idx_kernel(const int* __restrict__ idx, int twoE, int* flag) {
  __shared__ int ok;
  if (threadIdx.x == 0) ok = 1;
  __syncthreads();
  for (int i = threadIdx.x; i < 2048; i += blockDim.x) {
    int p = 2 * i + 1;
    if (p < twoE && idx[p] != 0) ok = 0;
  }
  __syncthreads();
  if (threadIdx.x == 0) flag[0] = ok;   // 1 => int64 storage, 0 => int32
}

__device__ __forceinline__ int edge_at(const int* __restrict__ idx, int pos, int is64) {
  return is64 ? idx[2 * pos] : idx[pos];
}

// ---------------- CSR build ----------------
__global__ void degree_kernel(const int* __restrict__ idx, int E, const int* __restrict__ flag,
                              int* __restrict__ row_start) {
  int e = blockIdx.x * blockDim.x + threadIdx.x;
  if (e >= E) return;
  int is64 = flag[0];
  int d = edge_at(idx, E + e, is64);
  atomicAdd(&row_start[d + 1], 1);
}

__global__ void scan_kernel(int* __restrict__ data, int n) {  // inclusive scan over n+1 entries
  __shared__ int sh[1024];
  __shared__ int carry;
  if (threadIdx.x == 0) carry = 0;
  __syncthreads();
  for (int base = 0; base < n + 1; base += 1024) {
    int i = base + threadIdx.x;
    int v = (i < n + 1) ? data[i] : 0;
    sh[threadIdx.x] = v;
    __syncthreads();
    for (int off = 1; off < 1024; off <<= 1) {
      int t = (threadIdx.x >= (unsigned)off) ? sh[threadIdx.x - off] : 0;
      __syncthreads();
      sh[threadIdx.x] += t;
      __syncthreads();
    }
    int inc = sh[threadIdx.x] + carry;
    if (i < n + 1) data[i] = inc;
    __syncthreads();
    if (threadIdx.x == 0) carry += sh[1023];
    __syncthreads();
  }
}

__global__ void scatter_kernel(const int* __restrict__ idx, int E, const int* __restrict__ flag,
                               const int* __restrict__ row_start, int* __restrict__ cursor,
                               int* __restrict__ csr) {
  int e = blockIdx.x * blockDim.x + threadIdx.x;
  if (e >= E) return;
  int is64 = flag[0];
  int s = edge_at(idx, e, is64);
  int d = edge_at(idx, E + e, is64);
  int pos = atomicAdd(&cursor[d], 1);
  csr[row_start[d] + pos] = s;
}

// ---------------- weight / input prep (fp32 -> fp16 hi/lo) ----------------
__global__ void prep_weights_kernel(const float* __restrict__ lin0_w, const float* __restrict__ w1,
                                    const float* __restrict__ w2, ushort* __restrict__ wH,
                                    ushort* __restrict__ wL, int totalw) {
  int i4 = (blockIdx.x * blockDim.x + threadIdx.x) * 4;
  if (i4 >= totalw) return;
  const int W = HQ * HQ;
  const float* src; int off;
  if (i4 < W)          { src = lin0_w; off = i4; }
  else if (i4 < 4 * W) { src = w1;     off = i4 - W; }
  else                 { src = w2;     off = i4 - 4 * W; }
  float4 v = *(const float4*)(src + off);
  uint2 ph, pl;
  split2(v.x, v.y, ph.x, pl.x);
  split2(v.z, v.w, ph.y, pl.y);
  *(uint2*)(wH + i4) = ph;
  *(uint2*)(wL + i4) = pl;
}

__global__ void prep_x_kernel(const float* __restrict__ x, ushort* __restrict__ xH,
                              ushort* __restrict__ xL, float* __restrict__ out0, int N, int MP) {
  int i4 = (blockIdx.x * blockDim.x + threadIdx.x) * 4;
  if (i4 >= MP * HQ) return;
  int row = i4 >> 9;
  uint2 ph, pl;
  if (row < N) {
    float4 v = *(const float4*)(x + i4);
    *(float4*)(out0 + i4) = v;                       // embs[0] = x (exact fp32 copy)
    split2(v.x, v.y, ph.x, pl.x);
    split2(v.z, v.w, ph.y, pl.y);
  } else {
    ph.x = ph.y = pl.x = pl.y = 0u;                  // zero pad rows
  }
  *(uint2*)(xH + i4) = ph;
  *(uint2*)(xL + i4) = pl;
}

// ---------------- GIN aggregation: z[n] = h[n] + sum_{j in nbr(n)} h[j] ----------------
__global__ void gather_kernel(const ushort* __restrict__ hH, const ushort* __restrict__ hL,
                              ushort* __restrict__ zH, ushort* __restrict__ zL,
                              const int* __restrict__ row_start, const int* __restrict__ csr) {
  const int n = blockIdx.x;
  const int c = threadIdx.x * 8;   // 64 lanes * 8 fp16 = 512
  float a[8];
  {
    uint4 vh = *(const uint4*)(hH + (size_t)n * HQ + c);
    uint4 vl = *(const uint4*)(hL + (size_t)n * HQ + c);
    float t0, t1, u0, u1;
    unpack2(vh.x, t0, t1); unpack2(vl.x, u0, u1); a[0] = t0 + u0; a[1] = t1 + u1;
    unpack2(vh.y, t0, t1); unpack2(vl.y, u0, u1); a[2] = t0 + u0; a[3] = t1 + u1;
    unpack2(vh.z, t0, t1); unpack2(vl.z, u0, u1); a[4] = t0 + u0; a[5] = t1 + u1;
    unpack2(vh.w, t0, t1); unpack2(vl.w, u0, u1); a[6] = t0 + u0; a[7] = t1 + u1;
  }
  const int s = row_start[n], e = row_start[n + 1];
  for (int j = s; j < e; ++j) {
    int src = csr[j];
    uint4 vh = *(const uint4*)(hH + (size_t)src * HQ + c);
    uint4 vl = *(const uint4*)(hL + (size_t)src * HQ + c);
    float t0, t1, u0, u1;
    unpack2(vh.x, t0, t1); unpack2(vl.x, u0, u1); a[0] += t0 + u0; a[1] += t1 + u1;
    unpack2(vh.y, t0, t1); unpack2(vl.y, u0, u1); a[2] += t0 + u0; a[3] += t1 + u1;
    unpack2(vh.z, t0, t1); unpack2(vl.z, u0, u1); a[4] += t0 + u0; a[5] += t1 + u1;
    unpack2(vh.w, t0, t1); unpack2(vl.w, u0, u1); a[6] += t0 + u0; a[7] += t1 + u1;
  }
  uint4 oh, ol;
  split2(a[0], a[1], oh.x, ol.x);
  split2(a[2], a[3], oh.y, ol.y);
  split2(a[4], a[5], oh.z, ol.z);
  split2(a[6], a[7], oh.w, ol.w);
  *(uint4*)(zH + (size_t)n * HQ + c) = oh;
  *(uint4*)(zL + (size_t)n * HQ + c) = ol;
}

// ---------------- GEMM: C[m,n] = A[m,:] . W[n,:] + bias[n], optional ReLU ----------------
// double-fp16: A = AH+AL, W = WH+WL; C ≈ AH·WH + AL·WH + AH·WL (fp32 acc).
// 128x128 tile, BK=32, 4 waves (2x2 of 64x64), mfma_f32_16x16x32_f16.
// STATS=1: additionally accumulate per-column sum/sumsq (rows < Nvalid) into sums[0..HQ-1]
// and sums[HQ..2*HQ-1] via wave-reduced atomics (replaces the separate bn_stats pass).
template <int RELU, int STATS>
__launch_bounds__(256)
__global__ void gemm3_kernel(const ushort* __restrict__ AH, const ushort* __restrict__ AL,
                             const ushort* __restrict__ WH, const ushort* __restrict__ WL,
                             const float* __restrict__ bias,
                             ushort* __restrict__ CH, ushort* __restrict__ CL,
                             float* __restrict__ sums, int Nvalid) {
  __shared__ ushort AsH[128 * 32];
  __shared__ ushort AsL[128 * 32];
  __shared__ ushort BsH[128 * 32];
  __shared__ ushort BsL[128 * 32];
  const int tid  = threadIdx.x;
  const int lane = tid & 63;
  const int wave = tid >> 6;
  const int m0 = blockIdx.x * 128;
  const int n0 = blockIdx.y * 128;
  const int wm = (wave >> 1) * 64;
  const int wn = (wave & 1) * 64;

  f32x4 acc[4][4];
#pragma unroll
  for (int i = 0; i < 4; ++i)
#pragma unroll
    for (int j = 0; j < 4; ++j) acc[i][j] = (f32x4){0.f, 0.f, 0.f, 0.f};

  const int fr = lane & 15;
  const int kb = lane >> 4;

  for (int kt = 0; kt < HQ; kt += 32) {
#pragma unroll
    for (int q = 0; q < 2; ++q) {
      const int ch  = q * 256 + tid;       // chunk id: row = ch>>2, col = (ch&3)*8
      const int row = ch >> 2;
      const int col = (ch & 3) * 8;
      const size_t ga = (size_t)(m0 + row) * HQ + kt + col;
      const size_t gb = (size_t)(n0 + row) * HQ + kt + col;
      gload_lds16(AH + ga, AsH + (size_t)(q * 256 + wave * 64) * 8);
      gload_lds16(AL + ga, AsL + (size_t)(q * 256 + wave * 64) * 8);
      gload_lds16(WH + gb, BsH + (size_t)(q * 256 + wave * 64) * 8);
      gload_lds16(WL + gb, BsL + (size_t)(q * 256 + wave * 64) * 8);
    }
    __syncthreads();
    f16x8 afH[4], afL[4], bfH[4], bfL[4];
#pragma unroll
    for (int i = 0; i < 4; ++i) {
      afH[i] = *(const f16x8*)&AsH[(wm + i * 16 + fr) * 32 + kb * 8];
      afL[i] = *(const f16x8*)&AsL[(wm + i * 16 + fr) * 32 + kb * 8];
    }
#pragma unroll
    for (int j = 0; j < 4; ++j) {
      bfH[j] = *(const f16x8*)&BsH[(wn + j * 16 + fr) * 32 + kb * 8];
      bfL[j] = *(const f16x8*)&BsL[(wn + j * 16 + fr) * 32 + kb * 8];
    }
#pragma unroll
    for (int i = 0; i < 4; ++i)
#pragma unroll
      for (int j = 0; j < 4; ++j)
        acc[i][j] = __builtin_amdgcn_mfma_f32_16x16x32_f16(afH[i], bfH[j], acc[i][j], 0, 0, 0);
#pragma unroll
    for (int i = 0; i < 4; ++i)
#pragma unroll
      for (int j = 0; j < 4; ++j)
        acc[i][j] = __builtin_amdgcn_mfma_f32_16x16x32_f16(afL[i], bfH[j], acc[i][j], 0, 0, 0);
#pragma unroll
    for (int i = 0; i < 4; ++i)
#pragma unroll
      for (int j = 0; j < 4; ++j)
        acc[i][j] = __builtin_amdgcn_mfma_f32_16x16x32_f16(afH[i], bfL[j], acc[i][j], 0, 0, 0);
    __syncthreads();
  }

  // epilogue: D col = lane&15, row = (lane>>4)*4 + r   [guide §3, m89/m91-verified]
#pragma unroll
  for (int j = 0; j < 4; ++j) {
    const int col = n0 + wn + j * 16 + fr;
    const float b = bias[col];
    float cs = 0.f, cq = 0.f;
#pragma unroll
    for (int i = 0; i < 4; ++i) {
      const int mb = m0 + wm + i * 16 + kb * 4;
#pragma unroll
      for (int r = 0; r < 4; ++r) {
        float v = acc[i][j][r] + b;
        if (RELU) v = fmaxf(v, 0.f);
        if (STATS) {
          const float vm = (mb + r < Nvalid) ? v : 0.f;
          cs += vm;
          cq += vm * vm;
        }
        ushort hi = f2h(v);
        float  lo = v - h2f(hi);
        CH[(size_t)(mb + r) * HQ + col] = hi;
        CL[(size_t)(mb + r) * HQ + col] = f2h(lo);
      }
    }
    if (STATS) {
      // reduce across the 4 kb lanes (same fr/col): lane ids differ in bits 4,5
      cs += __shfl_xor(cs, 16); cq += __shfl_xor(cq, 16);
      cs += __shfl_xor(cs, 32); cq += __shfl_xor(cq, 32);
      if (kb == 0) {
        atomicAdd(&sums[col], cs);
        atomicAdd(&sums[HQ + col], cq);
      }
    }
  }
}

// ---------------- BatchNorm finalize / apply ----------------
__global__ void bn_finalize_kernel(const float* __restrict__ sums, const float* __restrict__ gamma,
                                   const float* __restrict__ beta, float* __restrict__ scale,
                                   float* __restrict__ shift, int N) {
  int c = threadIdx.x;
  if (c < HQ) {
    float inv_n = 1.f / (float)N;
    float mu = sums[c] * inv_n;
    float var = fmaxf(sums[HQ + c] * inv_n - mu * mu, 0.f);
    float sc = gamma[c] * rsqrtf(var + BN_EPS);
    scale[c] = sc;
    shift[c] = beta[c] - mu * sc;
  }
}

__global__ void bn_apply_tanh_kernel(const ushort* __restrict__ zH, const ushort* __restrict__ zL,
                                     const float* __restrict__ scale, const float* __restrict__ shift,
                                     float* __restrict__ outp, ushort* __restrict__ hH,
                                     ushort* __restrict__ hL, int total) {
  int i8 = (blockIdx.x * blockDim.x + threadIdx.x) * 8;
  if (i8 >= total) return;
  int c0 = i8 & (HQ - 1);
  uint4 vh = *(const uint4*)(zH + i8);
  uint4 vl = *(const uint4*)(zL + i8);
  float a[8];
  {
    float t0, t1, u0, u1;
    unpack2(vh.x, t0, t1); unpack2(vl.x, u0, u1); a[0] = t0 + u0; a[1] = t1 + u1;
    unpack2(vh.y, t0, t1); unpack2(vl.y, u0, u1); a[2] = t0 + u0; a[3] = t1 + u1;
    unpack2(vh.z, t0, t1); unpack2(vl.z, u0, u1); a[4] = t0 + u0; a[5] = t1 + u1;
    unpack2(vh.w, t0, t1); unpack2(vl.w, u0, u1); a[6] = t0 + u0; a[7] = t1 + u1;
  }
  float4 sA = *(const float4*)(scale + c0);
  float4 sB = *(const float4*)(scale + c0 + 4);
  float4 hA = *(const float4*)(shift + c0);
  float4 hB = *(const float4*)(shift + c0 + 4);
  float y[8];
  y[0] = tanhf(fmaf(a[0], sA.x, hA.x));
  y[1] = tanhf(fmaf(a[1], sA.y, hA.y));
  y[2] = tanhf(fmaf(a[2], sA.z, hA.z));
  y[3] = tanhf(fmaf(a[3], sA.w, hA.w));
  y[4] = tanhf(fmaf(a[4], sB.x, hB.x));
  y[5] = tanhf(fmaf(a[5], sB.y, hB.y));
  y[6] = tanhf(fmaf(a[6], sB.z, hB.z));
  y[7] = tanhf(fmaf(a[7], sB.w, hB.w));
  *(float4*)(outp + i8)     = make_float4(y[0], y[1], y[2], y[3]);
  *(float4*)(outp + i8 + 4) = make_float4(y[4], y[5], y[6], y[7]);
  uint4 oh, ol;
  split2(y[0], y[1], oh.x, ol.x);
  split2(y[2], y[3], oh.y, ol.y);
  split2(y[4], y[5], oh.z, ol.z);
  split2(y[6], y[7], oh.w, ol.w);
  *(uint4*)(hH + i8) = oh;
  *(uint4*)(hL + i8) = ol;
}

// ---------------- launcher ----------------
extern "C" void kernel_launch(void* const* d_in, const int* in_sizes, int n_in,
                              void* d_out, int out_size, void* d_ws, size_t ws_size,
                              hipStream_t stream) {
  const float* x      = (const float*)d_in[0];
  const int*   idx    = (const int*)  d_in[1];
  const float* lin0_w = (const float*)d_in[2];
  const float* lin0_b = (const float*)d_in[3];
  const float* w1     = (const float*)d_in[4];
  const float* b1     = (const float*)d_in[5];
  const float* w2     = (const float*)d_in[6];
  const float* b2     = (const float*)d_in[7];
  const float* gamma  = (const float*)d_in[8];
  const float* beta   = (const float*)d_in[9];
  float* out = (float*)d_out;

  const int N    = in_sizes[0] / HQ;           // 10000
  const int twoE = in_sizes[1];                // 2*E
  const int E    = twoE / 2;
  const int L    = in_sizes[4] / (HQ * HQ);    // 3
  const int MT   = (N + 127) / 128;            // 79
  const int MP   = MT * 128;                   // 10112 (padded M)
  const size_t NH = (size_t)N * HQ;
  const size_t T  = (size_t)MP * HQ;           // padded tensor elems

  // workspace carve (all 16B-aligned)
  char* wsp = (char*)d_ws;
  int*    flag  = (int*)wsp;
  ushort* hbH   = (ushort*)(wsp + 256);
  ushort* hbL   = hbH + T;
  ushort* zAH   = hbL + T;
  ushort* zAL   = zAH + T;
  ushort* zBH   = zAL + T;
  ushort* zBL   = zBH + T;
  ushort* wHp   = zBL + T;
  ushort* wLp   = wHp + (size_t)(1 + 2 * L) * HQ * HQ;
  int*    row_start = (int*)(wLp + (size_t)(1 + 2 * L) * HQ * HQ);
  int*    cursor    = row_start + (N + 1);
  int*    csr       = cursor + N;
  float*  bnsums    = (float*)(csr + E);
  float*  bnscale   = bnsums + 2 * HQ;
  float*  bnshift   = bnscale + HQ;

  hipMemsetAsync(row_start, 0, (size_t)(2 * N + 1) * sizeof(int), stream);
  detect_idx_kernel<<<1, 256, 0, stream>>>(idx, twoE, flag);

  const int totalw = (1 + 2 * L) * HQ * HQ;
  prep_weights_kernel<<<(totalw / 4 + 255) / 256, 256, 0, stream>>>(lin0_w, w1, w2, wHp, wLp, totalw);
  prep_x_kernel<<<((int)(T / 4) + 255) / 256, 256, 0, stream>>>(x, zAH, zAL, out, N, MP);

  degree_kernel<<<(E + 255) / 256, 256, 0, stream>>>(idx, E, flag, row_start);
  scan_kernel<<<1, 1024, 0, stream>>>(row_start, N);
  scatter_kernel<<<(E + 255) / 256, 256, 0, stream>>>(idx, E, flag, row_start, cursor, csr);

  // h0 = x @ lin0_w.T + lin0_b   (no activation)
  gemm3_kernel<0, 0><<<dim3(MT, HQ / 128), 256, 0, stream>>>(
      zAH, zAL, wHp, wLp, lin0_b, hbH, hbL, nullptr, N);

  for (int l = 0; l < L; ++l) {
    gather_kernel<<<N, 64, 0, stream>>>(hbH, hbL, zAH, zAL, row_start, csr);
    gemm3_kernel<1, 0><<<dim3(MT, HQ / 128), 256, 0, stream>>>(
        zAH, zAL, wHp + (size_t)(1 + l) * HQ * HQ, wLp + (size_t)(1 + l) * HQ * HQ,
        b1 + (size_t)l * HQ, zBH, zBL, nullptr, N);
    hipMemsetAsync(bnsums, 0, 2 * HQ * sizeof(float), stream);
    gemm3_kernel<1, 1><<<dim3(MT, HQ / 128), 256, 0, stream>>>(
        zBH, zBL, wHp + (size_t)(1 + L + l) * HQ * HQ, wLp + (size_t)(1 + L + l) * HQ * HQ,
        b2 + (size_t)l * HQ, zAH, zAL, bnsums, N);
    bn_finalize_kernel<<<1, HQ, 0, stream>>>(bnsums, gamma + (size_t)l * HQ, beta + (size_t)l * HQ,
                                             bnscale, bnshift, N);
    bn_apply_tanh_kernel<<<((int)(NH / 8) + 255) / 256, 256, 0, stream>>>(
        zAH, zAL, bnscale, bnshift, out + (size_t)(l + 1) * NH, hbH, hbL, (int)NH);
  }
}